// Round 3
// baseline (177.780 us; speedup 1.0000x reference)
//
#include <hip/hip_runtime.h>

#define NN 50000
#define KE 32

using f32x4  = __attribute__((ext_vector_type(4))) float;
using f32x2  = __attribute__((ext_vector_type(2))) float;
using bf16x8 = __attribute__((ext_vector_type(8))) short;

__device__ __forceinline__ ushort f2bf(float f) {
    union { float f; unsigned u; } c; c.f = f;
    unsigned u = c.u;
    u += 0x7fffu + ((u >> 16) & 1u);        // round-to-nearest-even
    return (ushort)(u >> 16);
}

// HW packed f32->bf16 convert (RNE, same rounding as f2bf): 1 op per 2 values.
__device__ __forceinline__ unsigned cvtpk_bf16(float lo, float hi) {
    unsigned d;
    asm("v_cvt_pk_bf16_f32 %0, %1, %2" : "=v"(d) : "v"(lo), "v"(hi));
    return d;
}

// Packed f32 FMA: D = {a.x*b.x+c.x, a.y*b.y+c.y} in one instruction.
__device__ __forceinline__ f32x2 pk_fma(f32x2 a, f32x2 b, f32x2 c) {
    f32x2 d;
    asm("v_pk_fma_f32 %0, %1, %2, %3" : "=v"(d) : "v"(a), "v"(b), "v"(c));
    return d;
}

// Kernel A (blocks 0-1): fold attn_vec through W_q/W_k into bf16 Ub[16][128]
// (cols 0-3 = u_h, 4-7 = v_h, rows 8-15 zeroed for MFMA B-operand).
// Blocks 2..129: cast W_v into Bt[n][k] = bf16(W_v[k][n]).
__global__ __launch_bounds__(256) void prep_kernel(const float* __restrict__ Wq,
        const float* __restrict__ Wk, const float* __restrict__ av,
        const float* __restrict__ Wv, ushort* __restrict__ Ub,
        ushort* __restrict__ Bt) {
    const int g = blockIdx.x * 256 + threadIdx.x;
    if (blockIdx.x < 2) {
        const int h = g >> 7, i = g & 127;
        float su = 0.f, sv = 0.f;
#pragma unroll
        for (int d = 0; d < 32; ++d) {
            su += Wq[i * 128 + h * 32 + d] * av[h * 64 + d];
            sv += Wk[i * 128 + h * 32 + d] * av[h * 64 + 32 + d];
        }
        Ub[h * 128 + i] = f2bf(su);
        Ub[(4 + h) * 128 + i] = f2bf(sv);
        Ub[1024 + g * 2] = 0;               // zero rows 8..15
        Ub[1024 + g * 2 + 1] = 0;
    } else {
        const int idx = g - 512;            // 0..32767, coalesced read of Wv
        const int k = idx >> 7, n = idx & 127;
        Bt[n * 256 + k] = f2bf(Wv[idx]);
    }
}

// Kernel B v2: V = concat(x, emb) @ W_v via bf16 MFMA. Change vs v1:
// f32->bf16 conversions in staging + epilogue use v_cvt_pk_bf16_f32
// (1 op / 2 values, RNE — bit-identical to f2bf) instead of ~5-op bit
// twiddle: staging drops ~20 VALU/iter, epilogue ~16 VALU/pair.
__global__ __launch_bounds__(256) void vproj_mfma(const float* __restrict__ x,
        const float* __restrict__ emb, const ushort* __restrict__ Bt,
        const ushort* __restrict__ Ub, float* __restrict__ sq,
        float* __restrict__ sk, ushort* __restrict__ Vb) {
    __shared__ short As[64 * 264];          // 33.8 KB; reused (stride 132) for epilogue
    const int t = threadIdx.x;
    const int rbase = blockIdx.x * 64;

    // ---- stage A: 64 rows x 256 k, fp32 -> bf16 (packed cvt) ----
#pragma unroll
    for (int it = 0; it < 16; ++it) {
        const int li = it * 256 + t;        // float4-slot index
        const int row = li >> 6;
        const int c4 = li & 63;
        int rg = rbase + row; if (rg >= NN) rg = NN - 1;
        const float* sp = (c4 < 32) ? (x + (long)rg * 128 + c4 * 4)
                                    : (emb + (long)rg * 128 + (c4 - 32) * 4);
        float4 a = *(const float4*)sp;
        uint2 b;
        b.x = cvtpk_bf16(a.x, a.y);
        b.y = cvtpk_bf16(a.z, a.w);
        *(uint2*)&As[row * 264 + c4 * 4] = b;
    }
    __syncthreads();

    const int wv = t >> 6;
    const int lane = t & 63;
    const int lo = lane & 15;
    const int quad = lane >> 4;
    const int c0 = wv * 32;

    f32x4 acc[4][2] = {};
    for (int ks = 0; ks < 8; ++ks) {
        const int kb = ks * 32 + quad * 8;
        bf16x8 bf0 = *(const bf16x8*)(Bt + (c0 + lo) * 256 + kb);
        bf16x8 bf1 = *(const bf16x8*)(Bt + (c0 + 16 + lo) * 256 + kb);
#pragma unroll
        for (int rt = 0; rt < 4; ++rt) {
            bf16x8 af = *(const bf16x8*)&As[(rt * 16 + lo) * 264 + kb];
            acc[rt][0] = __builtin_amdgcn_mfma_f32_16x16x32_bf16(af, bf0, acc[rt][0], 0, 0, 0);
            acc[rt][1] = __builtin_amdgcn_mfma_f32_16x16x32_bf16(af, bf1, acc[rt][1], 0, 0, 0);
        }
    }

    // ---- scores: wave wv handles rows wv*16..+15; K = emb dims (As cols 128+) ----
    f32x4 sacc = {};
#pragma unroll
    for (int ks = 0; ks < 4; ++ks) {
        const int kk = ks * 32 + quad * 8;
        bf16x8 saf = *(const bf16x8*)&As[(wv * 16 + lo) * 264 + 128 + kk];
        bf16x8 sbf = *(const bf16x8*)(Ub + lo * 128 + kk);
        sacc = __builtin_amdgcn_mfma_f32_16x16x32_bf16(saf, sbf, sacc, 0, 0, 0);
    }
    if (lo < 8) {
#pragma unroll
        for (int r = 0; r < 4; ++r) {
            const int row = rbase + wv * 16 + quad * 4 + r;
            if (row < NN) {
                if (lo < 4) sq[(long)row * 4 + lo] = sacc[r];
                else        sk[(long)row * 4 + lo - 4] = sacc[r];
            }
        }
    }

    // ---- epilogue: regs -> LDS (bf16 via packed cvt) -> coalesced global ----
    __syncthreads();                        // all As reads done
#pragma unroll
    for (int rt = 0; rt < 4; ++rt)
#pragma unroll
        for (int ct = 0; ct < 2; ++ct) {
            const int base = (rt * 16 + quad * 4) * 132 + c0 + ct * 16 + lo;
            const unsigned u01 = cvtpk_bf16(acc[rt][ct][0], acc[rt][ct][1]);
            const unsigned u23 = cvtpk_bf16(acc[rt][ct][2], acc[rt][ct][3]);
            As[base]       = (short)u01;
            As[base + 132] = (short)(u01 >> 16);
            As[base + 264] = (short)u23;
            As[base + 396] = (short)(u23 >> 16);
        }
    __syncthreads();
#pragma unroll
    for (int i = 0; i < 4; ++i) {
        const int idx = i * 256 + t;
        const int row = idx >> 4;
        const int seg = idx & 15;
        const int grow = rbase + row;
        if (grow < NN)
            *(bf16x8*)(Vb + (long)grow * 128 + seg * 8) =
                *(const bf16x8*)&As[row * 132 + seg * 8];
    }
}

// Kernel C v4: per-node softmax + weighted gather. Changes vs v3 (which
// proved gather-latency is NOT dominant: 8-deep MLP bought only 6%):
// attack issued-instruction count.
//  (1) softmax max-subtraction DROPPED: alpha = exp(e)/sum(exp(e)) is
//      mathematically identical (max cancels); e bounded (|e|<~30) so no
//      overflow. Kills 10 shuffles + 10 fmax + a 5-deep serial chain.
//  (2) FMA burst uses v_pk_fma_f32: 3 instr per column pair, was 4.
//  (3) alpha divide -> v_rcp (rel err 1e-7, invisible vs bf16 absmax).
__global__ __launch_bounds__(256, 4) void aggregate_kernel(const int* __restrict__ src,
        const float* __restrict__ sq, const float* __restrict__ sk,
        const ushort* __restrict__ Vb, const float* __restrict__ gamma,
        const float* __restrict__ beta, float* __restrict__ out) {
    __shared__ float s_alpha[4][32][4];
    const int w = threadIdx.x >> 6;
    const int lane = threadIdx.x & 63;
    const int n = blockIdx.x * 4 + w;
    const int g  = lane >> 4;      // edge subgroup 0..3
    const int li = lane & 15;      // column group: cols li*8 .. li*8+7
    const int h  = li >> 2;        // head of these 8 cols

    // ---- issue this lane's 8 V-row gathers ASAP (independent of alpha) ----
    const long ebase = (long)n * KE;
    int s_e[8];
#pragma unroll
    for (int it = 0; it < 8; ++it)
        s_e[it] = src[ebase + it * 4 + g];          // 4 distinct words/wave: L1 broadcast
    const char* vb = (const char*)Vb;
    uint4 p[8];
#pragma unroll
    for (int it = 0; it < 8; ++it) {
        const unsigned off = ((unsigned)s_e[it] << 8) + (unsigned)(li * 16);
        p[it] = *(const uint4*)(vb + off);          // saddr + 32-bit voffset
    }

    // ---- softmax over the node's 32 edges, all 64 lanes (2 heads each) ----
    {
        const int e_id = lane & 31;
        const int hp = (lane >> 5) * 2;             // heads {0,1} or {2,3}
        const int s = src[ebase + e_id];
        float2 sk2 = *(const float2*)(sk + (long)s * 4 + hp);
        float2 sq2 = *(const float2*)(sq + (long)n * 4 + hp);
        float e0 = sq2.x + sk2.x, e1 = sq2.y + sk2.y;
        e0 = e0 > 0.f ? e0 : 0.2f * e0;
        e1 = e1 > 0.f ? e1 : 0.2f * e1;
        float x0 = __expf(e0), x1 = __expf(e1);     // no max-sub: cancels exactly
        float u0 = x0, u1 = x1;
#pragma unroll
        for (int off = 16; off > 0; off >>= 1) {
            u0 += __shfl_xor(u0, off);
            u1 += __shfl_xor(u1, off);
        }
        float2 al;
        al.x = x0 * __builtin_amdgcn_rcpf(u0 + 1e-8f);
        al.y = x1 * __builtin_amdgcn_rcpf(u1 + 1e-8f);
        *(float2*)&s_alpha[w][e_id][hp] = al;
    }
    // wave-internal producer->consumer: no block barrier needed
    __asm__ volatile("s_waitcnt lgkmcnt(0)" ::: "memory");

    // pin: p[] must be live here -> loads cannot sink into the FMA loop
#pragma unroll
    for (int it = 0; it < 8; ++it)
        __asm__ volatile("" : "+v"(p[it].x), "+v"(p[it].y), "+v"(p[it].z), "+v"(p[it].w));

    // ---- preload this lane's 8 alphas, then packed-FMA burst ----
    float a[8];
#pragma unroll
    for (int it = 0; it < 8; ++it)
        a[it] = s_alpha[w][it * 4 + g][h];

    f32x2 z2[4] = {};
#pragma unroll
    for (int it = 0; it < 8; ++it) {
        const unsigned pc[4] = { p[it].x, p[it].y, p[it].z, p[it].w };
        const f32x2 a2 = { a[it], a[it] };
#pragma unroll
        for (int j = 0; j < 4; ++j) {
            union { unsigned u; float f; } ve, vo;
            ve.u = pc[j] << 16;                     // even col (lo bf16)
            vo.u = pc[j] & 0xffff0000u;             // odd col (hi bf16)
            const f32x2 v = { ve.f, vo.f };
            z2[j] = pk_fma(a2, v, z2[j]);
        }
    }
    float z[8];
#pragma unroll
    for (int j = 0; j < 4; ++j) { z[2 * j] = z2[j].x; z[2 * j + 1] = z2[j].y; }

    // sum over the 4 edge subgroups (lanes differing in bits 4-5)
#pragma unroll
    for (int j = 0; j < 8; ++j) {
        z[j] += __shfl_xor(z[j], 16);
        z[j] += __shfl_xor(z[j], 32);
    }
    // ELU (replicated across subgroups — consistent)
    float s1 = 0.f, s2 = 0.f;
#pragma unroll
    for (int j = 0; j < 8; ++j) {
        z[j] = z[j] > 0.f ? z[j] : __expf(z[j]) - 1.f;
        s1 += z[j];
        s2 += z[j] * z[j];
    }
    // LayerNorm sums over the 16 column groups
#pragma unroll
    for (int off = 8; off > 0; off >>= 1) {
        s1 += __shfl_xor(s1, off);
        s2 += __shfl_xor(s2, off);
    }
    const float mu = s1 * (1.f / 128.f);
    const float var = s2 * (1.f / 128.f) - mu * mu;
    const float rstd = rsqrtf(var + 1e-5f);
    if (g < 2) {
        const int c0 = li * 8 + g * 4;
        float4 ga = *(const float4*)(gamma + c0);
        float4 be = *(const float4*)(beta + c0);
        float4 o;
        o.x = (z[g * 4 + 0] - mu) * rstd * ga.x + be.x;
        o.y = (z[g * 4 + 1] - mu) * rstd * ga.y + be.y;
        o.z = (z[g * 4 + 2] - mu) * rstd * ga.z + be.z;
        o.w = (z[g * 4 + 3] - mu) * rstd * ga.w + be.w;
        *(float4*)(out + (long)n * 128 + c0) = o;
    }
}

extern "C" void kernel_launch(void* const* d_in, const int* in_sizes, int n_in,
                              void* d_out, int out_size, void* d_ws, size_t ws_size,
                              hipStream_t stream) {
    const float* x     = (const float*)d_in[0];
    const float* emb   = (const float*)d_in[1];
    const int*   edge  = (const int*)d_in[2];
    const float* Wq    = (const float*)d_in[3];
    const float* Wk    = (const float*)d_in[4];
    const float* Wv    = (const float*)d_in[5];
    const float* av    = (const float*)d_in[6];
    const float* gamma = (const float*)d_in[7];
    const float* beta  = (const float*)d_in[8];
    float* out = (float*)d_out;

    char* ws = (char*)d_ws;
    ushort* Ub = (ushort*)(ws + 0);             //   4096 B (16x128 bf16)
    ushort* Bt = (ushort*)(ws + 4096);          //  65536 B
    float*  sq = (float*)(ws + 69632);          // 800000 B
    float*  sk = (float*)(ws + 869632);         // 800000 B
    ushort* Vb = (ushort*)(ws + 1669632);       // 12.8 MB

    prep_kernel<<<130, 256, 0, stream>>>(Wq, Wk, av, Wv, Ub, Bt);
    vproj_mfma<<<(NN + 63) / 64, 256, 0, stream>>>(x, emb, Bt, Ub, sq, sk, Vb);
    aggregate_kernel<<<NN / 4, 256, 0, stream>>>(edge, sq, sk, Vb, gamma, beta, out);
}

// Round 4
// 170.951 us; speedup vs baseline: 1.0399x; 1.0399x over previous
//
#include <hip/hip_runtime.h>

#define NN 50000
#define KE 32

using f32x4  = __attribute__((ext_vector_type(4))) float;
using f32x2  = __attribute__((ext_vector_type(2))) float;
using bf16x8 = __attribute__((ext_vector_type(8))) short;

__device__ __forceinline__ ushort f2bf(float f) {
    union { float f; unsigned u; } c; c.f = f;
    unsigned u = c.u;
    u += 0x7fffu + ((u >> 16) & 1u);        // round-to-nearest-even
    return (ushort)(u >> 16);
}

// HW packed f32->bf16 convert (RNE, same rounding as f2bf): 1 op per 2 values.
__device__ __forceinline__ unsigned cvtpk_bf16(float lo, float hi) {
    unsigned d;
    asm("v_cvt_pk_bf16_f32 %0, %1, %2" : "=v"(d) : "v"(lo), "v"(hi));
    return d;
}

// Packed f32 FMA: D = {a.x*b.x+c.x, a.y*b.y+c.y} in one instruction.
__device__ __forceinline__ f32x2 pk_fma(f32x2 a, f32x2 b, f32x2 c) {
    f32x2 d;
    asm("v_pk_fma_f32 %0, %1, %2, %3" : "=v"(d) : "v"(a), "v"(b), "v"(c));
    return d;
}

// Kernel A (blocks 0-1): fold attn_vec through W_q/W_k into bf16 Ub[16][128]
// (cols 0-3 = u_h, 4-7 = v_h, rows 8-15 zeroed for MFMA B-operand).
// Blocks 2..129: cast W_v into Bt[n][k] = bf16(W_v[k][n]).
__global__ __launch_bounds__(256) void prep_kernel(const float* __restrict__ Wq,
        const float* __restrict__ Wk, const float* __restrict__ av,
        const float* __restrict__ Wv, ushort* __restrict__ Ub,
        ushort* __restrict__ Bt) {
    const int g = blockIdx.x * 256 + threadIdx.x;
    if (blockIdx.x < 2) {
        const int h = g >> 7, i = g & 127;
        float su = 0.f, sv = 0.f;
#pragma unroll
        for (int d = 0; d < 32; ++d) {
            su += Wq[i * 128 + h * 32 + d] * av[h * 64 + d];
            sv += Wk[i * 128 + h * 32 + d] * av[h * 64 + 32 + d];
        }
        Ub[h * 128 + i] = f2bf(su);
        Ub[(4 + h) * 128 + i] = f2bf(sv);
        Ub[1024 + g * 2] = 0;               // zero rows 8..15
        Ub[1024 + g * 2 + 1] = 0;
    } else {
        const int idx = g - 512;            // 0..32767, coalesced read of Wv
        const int k = idx >> 7, n = idx & 127;
        Bt[n * 256 + k] = f2bf(Wv[idx]);
    }
}

// Kernel B v3: V = concat(x, emb) @ W_v via bf16 MFMA. Change vs v2:
// ALL 16 B-fragment loads (Bt, 64 KB, loop-invariant per wave) hoisted to
// registers BEFORE A-staging — their ~200cy L2 latency hides under the
// staging loads + barrier, and the K-loop becomes pure ds_read_b128+MFMA
// (no global access in the hot loop). __launch_bounds__(256,3): LDS caps
// occupancy at 4 blocks/CU anyway, so allow ~170 VGPR for the 64-reg
// B-fragment file + 32-reg acc without spill.
__global__ __launch_bounds__(256, 3) void vproj_mfma(const float* __restrict__ x,
        const float* __restrict__ emb, const ushort* __restrict__ Bt,
        const ushort* __restrict__ Ub, float* __restrict__ sq,
        float* __restrict__ sk, ushort* __restrict__ Vb) {
    __shared__ short As[64 * 264];          // 33.8 KB; reused (stride 132) for epilogue
    const int t = threadIdx.x;
    const int rbase = blockIdx.x * 64;
    const int wv = t >> 6;
    const int lane = t & 63;
    const int lo = lane & 15;
    const int quad = lane >> 4;
    const int c0 = wv * 32;

    // ---- hoist: B fragments for all 8 K-steps -> 64 VGPRs (16 dwordx4) ----
    bf16x8 bf0[8], bf1[8];
#pragma unroll
    for (int ks = 0; ks < 8; ++ks) {
        const int kb = ks * 32 + quad * 8;
        bf0[ks] = *(const bf16x8*)(Bt + (c0 + lo) * 256 + kb);
        bf1[ks] = *(const bf16x8*)(Bt + (c0 + 16 + lo) * 256 + kb);
    }

    // ---- stage A: 64 rows x 256 k, fp32 -> bf16 (packed cvt) ----
#pragma unroll
    for (int it = 0; it < 16; ++it) {
        const int li = it * 256 + t;        // float4-slot index
        const int row = li >> 6;
        const int c4 = li & 63;
        int rg = rbase + row; if (rg >= NN) rg = NN - 1;
        const float* sp = (c4 < 32) ? (x + (long)rg * 128 + c4 * 4)
                                    : (emb + (long)rg * 128 + (c4 - 32) * 4);
        float4 a = *(const float4*)sp;
        uint2 b;
        b.x = cvtpk_bf16(a.x, a.y);
        b.y = cvtpk_bf16(a.z, a.w);
        *(uint2*)&As[row * 264 + c4 * 4] = b;
    }
    __syncthreads();

    // pin: B fragments must be resident here (can't be re-sunk into loop)
#pragma unroll
    for (int ks = 0; ks < 8; ++ks) {
        __asm__ volatile("" : "+v"(bf0[ks]));
        __asm__ volatile("" : "+v"(bf1[ks]));
    }

    f32x4 acc[4][2] = {};
#pragma unroll
    for (int ks = 0; ks < 8; ++ks) {
        const int kb = ks * 32 + quad * 8;
#pragma unroll
        for (int rt = 0; rt < 4; ++rt) {
            bf16x8 af = *(const bf16x8*)&As[(rt * 16 + lo) * 264 + kb];
            acc[rt][0] = __builtin_amdgcn_mfma_f32_16x16x32_bf16(af, bf0[ks], acc[rt][0], 0, 0, 0);
            acc[rt][1] = __builtin_amdgcn_mfma_f32_16x16x32_bf16(af, bf1[ks], acc[rt][1], 0, 0, 0);
        }
    }

    // ---- scores: wave wv handles rows wv*16..+15; K = emb dims (As cols 128+) ----
    f32x4 sacc = {};
#pragma unroll
    for (int ks = 0; ks < 4; ++ks) {
        const int kk = ks * 32 + quad * 8;
        bf16x8 saf = *(const bf16x8*)&As[(wv * 16 + lo) * 264 + 128 + kk];
        bf16x8 sbf = *(const bf16x8*)(Ub + lo * 128 + kk);
        sacc = __builtin_amdgcn_mfma_f32_16x16x32_bf16(saf, sbf, sacc, 0, 0, 0);
    }
    if (lo < 8) {
#pragma unroll
        for (int r = 0; r < 4; ++r) {
            const int row = rbase + wv * 16 + quad * 4 + r;
            if (row < NN) {
                if (lo < 4) sq[(long)row * 4 + lo] = sacc[r];
                else        sk[(long)row * 4 + lo - 4] = sacc[r];
            }
        }
    }

    // ---- epilogue: regs -> LDS (bf16 via packed cvt) -> coalesced global ----
    __syncthreads();                        // all As reads done
#pragma unroll
    for (int rt = 0; rt < 4; ++rt)
#pragma unroll
        for (int ct = 0; ct < 2; ++ct) {
            const int base = (rt * 16 + quad * 4) * 132 + c0 + ct * 16 + lo;
            const unsigned u01 = cvtpk_bf16(acc[rt][ct][0], acc[rt][ct][1]);
            const unsigned u23 = cvtpk_bf16(acc[rt][ct][2], acc[rt][ct][3]);
            As[base]       = (short)u01;
            As[base + 132] = (short)(u01 >> 16);
            As[base + 264] = (short)u23;
            As[base + 396] = (short)(u23 >> 16);
        }
    __syncthreads();
#pragma unroll
    for (int i = 0; i < 4; ++i) {
        const int idx = i * 256 + t;
        const int row = idx >> 4;
        const int seg = idx & 15;
        const int grow = rbase + row;
        if (grow < NN)
            *(bf16x8*)(Vb + (long)grow * 128 + seg * 8) =
                *(const bf16x8*)&As[row * 132 + seg * 8];
    }
}

// Kernel C v4 (unchanged from R3): per-node softmax + weighted gather.
__global__ __launch_bounds__(256, 4) void aggregate_kernel(const int* __restrict__ src,
        const float* __restrict__ sq, const float* __restrict__ sk,
        const ushort* __restrict__ Vb, const float* __restrict__ gamma,
        const float* __restrict__ beta, float* __restrict__ out) {
    __shared__ float s_alpha[4][32][4];
    const int w = threadIdx.x >> 6;
    const int lane = threadIdx.x & 63;
    const int n = blockIdx.x * 4 + w;
    const int g  = lane >> 4;      // edge subgroup 0..3
    const int li = lane & 15;      // column group: cols li*8 .. li*8+7
    const int h  = li >> 2;        // head of these 8 cols

    // ---- issue this lane's 8 V-row gathers ASAP (independent of alpha) ----
    const long ebase = (long)n * KE;
    int s_e[8];
#pragma unroll
    for (int it = 0; it < 8; ++it)
        s_e[it] = src[ebase + it * 4 + g];          // 4 distinct words/wave: L1 broadcast
    const char* vb = (const char*)Vb;
    uint4 p[8];
#pragma unroll
    for (int it = 0; it < 8; ++it) {
        const unsigned off = ((unsigned)s_e[it] << 8) + (unsigned)(li * 16);
        p[it] = *(const uint4*)(vb + off);          // saddr + 32-bit voffset
    }

    // ---- softmax over the node's 32 edges, all 64 lanes (2 heads each) ----
    {
        const int e_id = lane & 31;
        const int hp = (lane >> 5) * 2;             // heads {0,1} or {2,3}
        const int s = src[ebase + e_id];
        float2 sk2 = *(const float2*)(sk + (long)s * 4 + hp);
        float2 sq2 = *(const float2*)(sq + (long)n * 4 + hp);
        float e0 = sq2.x + sk2.x, e1 = sq2.y + sk2.y;
        e0 = e0 > 0.f ? e0 : 0.2f * e0;
        e1 = e1 > 0.f ? e1 : 0.2f * e1;
        float x0 = __expf(e0), x1 = __expf(e1);     // no max-sub: cancels exactly
        float u0 = x0, u1 = x1;
#pragma unroll
        for (int off = 16; off > 0; off >>= 1) {
            u0 += __shfl_xor(u0, off);
            u1 += __shfl_xor(u1, off);
        }
        float2 al;
        al.x = x0 * __builtin_amdgcn_rcpf(u0 + 1e-8f);
        al.y = x1 * __builtin_amdgcn_rcpf(u1 + 1e-8f);
        *(float2*)&s_alpha[w][e_id][hp] = al;
    }
    // wave-internal producer->consumer: no block barrier needed
    __asm__ volatile("s_waitcnt lgkmcnt(0)" ::: "memory");

    // pin: p[] must be live here -> loads cannot sink into the FMA loop
#pragma unroll
    for (int it = 0; it < 8; ++it)
        __asm__ volatile("" : "+v"(p[it].x), "+v"(p[it].y), "+v"(p[it].z), "+v"(p[it].w));

    // ---- preload this lane's 8 alphas, then packed-FMA burst ----
    float a[8];
#pragma unroll
    for (int it = 0; it < 8; ++it)
        a[it] = s_alpha[w][it * 4 + g][h];

    f32x2 z2[4] = {};
#pragma unroll
    for (int it = 0; it < 8; ++it) {
        const unsigned pc[4] = { p[it].x, p[it].y, p[it].z, p[it].w };
        const f32x2 a2 = { a[it], a[it] };
#pragma unroll
        for (int j = 0; j < 4; ++j) {
            union { unsigned u; float f; } ve, vo;
            ve.u = pc[j] << 16;                     // even col (lo bf16)
            vo.u = pc[j] & 0xffff0000u;             // odd col (hi bf16)
            const f32x2 v = { ve.f, vo.f };
            z2[j] = pk_fma(a2, v, z2[j]);
        }
    }
    float z[8];
#pragma unroll
    for (int j = 0; j < 4; ++j) { z[2 * j] = z2[j].x; z[2 * j + 1] = z2[j].y; }

    // sum over the 4 edge subgroups (lanes differing in bits 4-5)
#pragma unroll
    for (int j = 0; j < 8; ++j) {
        z[j] += __shfl_xor(z[j], 16);
        z[j] += __shfl_xor(z[j], 32);
    }
    // ELU (replicated across subgroups — consistent)
    float s1 = 0.f, s2 = 0.f;
#pragma unroll
    for (int j = 0; j < 8; ++j) {
        z[j] = z[j] > 0.f ? z[j] : __expf(z[j]) - 1.f;
        s1 += z[j];
        s2 += z[j] * z[j];
    }
    // LayerNorm sums over the 16 column groups
#pragma unroll
    for (int off = 8; off > 0; off >>= 1) {
        s1 += __shfl_xor(s1, off);
        s2 += __shfl_xor(s2, off);
    }
    const float mu = s1 * (1.f / 128.f);
    const float var = s2 * (1.f / 128.f) - mu * mu;
    const float rstd = rsqrtf(var + 1e-5f);
    if (g < 2) {
        const int c0 = li * 8 + g * 4;
        float4 ga = *(const float4*)(gamma + c0);
        float4 be = *(const float4*)(beta + c0);
        float4 o;
        o.x = (z[g * 4 + 0] - mu) * rstd * ga.x + be.x;
        o.y = (z[g * 4 + 1] - mu) * rstd * ga.y + be.y;
        o.z = (z[g * 4 + 2] - mu) * rstd * ga.z + be.z;
        o.w = (z[g * 4 + 3] - mu) * rstd * ga.w + be.w;
        *(float4*)(out + (long)n * 128 + c0) = o;
    }
}

extern "C" void kernel_launch(void* const* d_in, const int* in_sizes, int n_in,
                              void* d_out, int out_size, void* d_ws, size_t ws_size,
                              hipStream_t stream) {
    const float* x     = (const float*)d_in[0];
    const float* emb   = (const float*)d_in[1];
    const int*   edge  = (const int*)d_in[2];
    const float* Wq    = (const float*)d_in[3];
    const float* Wk    = (const float*)d_in[4];
    const float* Wv    = (const float*)d_in[5];
    const float* av    = (const float*)d_in[6];
    const float* gamma = (const float*)d_in[7];
    const float* beta  = (const float*)d_in[8];
    float* out = (float*)d_out;

    char* ws = (char*)d_ws;
    ushort* Ub = (ushort*)(ws + 0);             //   4096 B (16x128 bf16)
    ushort* Bt = (ushort*)(ws + 4096);          //  65536 B
    float*  sq = (float*)(ws + 69632);          // 800000 B
    float*  sk = (float*)(ws + 869632);         // 800000 B
    ushort* Vb = (ushort*)(ws + 1669632);       // 12.8 MB

    prep_kernel<<<130, 256, 0, stream>>>(Wq, Wk, av, Wv, Ub, Bt);
    vproj_mfma<<<(NN + 63) / 64, 256, 0, stream>>>(x, emb, Bt, Ub, sq, sk, Vb);
    aggregate_kernel<<<NN / 4, 256, 0, stream>>>(edge, sq, sk, Vb, gamma, beta, out);
}